// Round 5
// baseline (239.879 us; speedup 1.0000x reference)
//
#include <hip/hip_runtime.h>
#include <math.h>

// ---------------------------------------------------------------------------
// Problem constants
// ---------------------------------------------------------------------------
#define N_SEQ   896
#define DH      3072
#define NCTX    64
#define JLEN    127
#define DC      1024
#define HEADS   8
#define DHEAD   64
#define INNER   512   // HEADS*DHEAD
#define MKV     8128  // NCTX*JLEN
#define MKVPAD  8192

typedef __bf16 bf16x8 __attribute__((ext_vector_type(8)));
typedef float  f32x4  __attribute__((ext_vector_type(4)));

// workspace float offsets
#define OFF_EDOT   0LL
#define OFF_QBF    (OFF_EDOT + N_SEQ)
#define OFF_KBF    (OFF_QBF  + (long long)N_SEQ*INNER/2)     // bf16 896x512
#define OFF_VPM    (OFF_KBF  + (long long)NCTX*128*INNER/2)  // fp32 8128x8
#define OFF_VPNULL (OFF_VPM  + (long long)MKV*8)
#define OFF_WOP    (OFF_VPNULL + 8)
#define OFF_BOP    (OFF_WOP  + INNER)
#define OFF_SBUF   (OFF_BOP  + 16)                           // fp32 64*8*896
#define OFF_ANQ    (OFF_SBUF + (long long)NCTX*HEADS*N_SEQ)  // bf16 896x3072
#define OFF_ANKV   (OFF_ANQ  + (long long)N_SEQ*DH/2)        // bf16 8192x1024
#define OFF_WQT    (OFF_ANKV + (long long)MKVPAD*DC/2)       // bf16 512x3072
#define OFF_WKT    (OFF_WQT  + (long long)INNER*DH/2)        // bf16 512x1024
#define OFF_WVPT   (OFF_WKT  + (long long)INNER*DC/2)        // bf16 16x1024
#define OFF_QSL    (OFF_WVPT + 16*1024/2)                    // fp32 8 x 896x512

// ---------------------------------------------------------------------------
// async global->LDS 16B helper
// ---------------------------------------------------------------------------
__device__ __forceinline__ void async_copy16(const __bf16* g, __bf16* l) {
    __builtin_amdgcn_global_load_lds(
        (const __attribute__((address_space(1))) unsigned int*)g,
        (__attribute__((address_space(3))) unsigned int*)l,
        16, 0, 0);
}

// ---------------------------------------------------------------------------
// LN row helper: stats + normalize + bf16 convert (+ optional Wp dot)
// ---------------------------------------------------------------------------
template <int P>
__device__ __forceinline__
void ln_row(const float* __restrict__ x,
            const float* __restrict__ gamma, const float* __restrict__ beta,
            const float* __restrict__ wp,
            __bf16* __restrict__ o, float* __restrict__ dotout) {
    const int K = P * 1024;
    float4 xv[P];
    float s = 0.f, ss = 0.f, dp = 0.f;
    #pragma unroll
    for (int p = 0; p < P; ++p) {
        xv[p] = *(const float4*)&x[p * 1024 + threadIdx.x * 4];
        s  += xv[p].x + xv[p].y + xv[p].z + xv[p].w;
        ss += xv[p].x * xv[p].x + xv[p].y * xv[p].y
            + xv[p].z * xv[p].z + xv[p].w * xv[p].w;
        if (wp) {
            float4 w4 = *(const float4*)&wp[p * 1024 + threadIdx.x * 4];
            dp += xv[p].x * w4.x + xv[p].y * w4.y + xv[p].z * w4.z + xv[p].w * w4.w;
        }
    }
    #pragma unroll
    for (int ofs = 32; ofs > 0; ofs >>= 1) {
        s  += __shfl_down(s,  ofs);
        ss += __shfl_down(ss, ofs);
        dp += __shfl_down(dp, ofs);
    }
    __shared__ float red[3][4];
    __shared__ float sh_mu, sh_rstd;
    int lane = threadIdx.x & 63, w = threadIdx.x >> 6;
    if (lane == 0) { red[0][w] = s; red[1][w] = ss; red[2][w] = dp; }
    __syncthreads();
    if (threadIdx.x == 0) {
        float S  = red[0][0] + red[0][1] + red[0][2] + red[0][3];
        float SS = red[1][0] + red[1][1] + red[1][2] + red[1][3];
        float m = S / K;
        sh_mu = m;
        sh_rstd = rsqrtf(SS / K - m * m + 1e-5f);
        if (dotout) *dotout = red[2][0] + red[2][1] + red[2][2] + red[2][3];
    }
    __syncthreads();
    float m = sh_mu, r = sh_rstd;
    #pragma unroll
    for (int p = 0; p < P; ++p) {
        int col = p * 1024 + threadIdx.x * 4;
        float4 g4 = *(const float4*)&gamma[col];
        float4 b4 = *(const float4*)&beta[col];
        __bf16 ov[4];
        ov[0] = (__bf16)((xv[p].x - m) * r * g4.x + b4.x);
        ov[1] = (__bf16)((xv[p].y - m) * r * g4.y + b4.y);
        ov[2] = (__bf16)((xv[p].z - m) * r * g4.z + b4.z);
        ov[3] = (__bf16)((xv[p].w - m) * r * g4.w + b4.w);
        *(ushort4*)&o[col] = *(ushort4*)ov;
    }
}

// ---------------------------------------------------------------------------
// K1: fused ln_q (896) + ln_kv (8128) + wop/bop (513) by block range
// ---------------------------------------------------------------------------
__global__ __launch_bounds__(256)
void ln_wop_kernel(const float* __restrict__ emb, const float* __restrict__ ctx,
                   const float* __restrict__ qg, const float* __restrict__ qb,
                   const float* __restrict__ kvg, const float* __restrict__ kvb,
                   const float* __restrict__ Wp, const float* __restrict__ Wo,
                   const float* __restrict__ bo,
                   __bf16* __restrict__ anq, __bf16* __restrict__ ankv,
                   float* __restrict__ edot, float* __restrict__ wop,
                   float* __restrict__ bop) {
    int b = blockIdx.x;
    if (b < N_SEQ) {
        ln_row<3>(emb + (long long)b * DH, qg, qb, Wp,
                  anq + (long long)b * DH, edot + b);
    } else if (b < N_SEQ + MKV) {
        int r = b - N_SEQ;
        ln_row<1>(ctx + (long long)r * DC, kvg, kvb, nullptr,
                  ankv + (long long)r * DC, nullptr);
    } else {
        int r = b - (N_SEQ + MKV);   // 0..512
        const float* src = (r < INNER) ? (Wo + (long long)r * DH) : bo;
        float s = 0.f;
        for (int k = threadIdx.x; k < DH; k += 256) s += src[k] * Wp[k];
        #pragma unroll
        for (int o = 32; o > 0; o >>= 1) s += __shfl_down(s, o);
        __shared__ float red2[4];
        int lane = threadIdx.x & 63, w = threadIdx.x >> 6;
        if (lane == 0) red2[w] = s;
        __syncthreads();
        if (threadIdx.x == 0) {
            float S = red2[0] + red2[1] + red2[2] + red2[3];
            if (r < INNER) wop[r] = S; else *bop = S;
        }
    }
}

// ---------------------------------------------------------------------------
// K2: fused weight prep: WQT transpose (1536) + WKT transpose (512) +
//     wvpt (32) + null_k/vpnull/zero (1)
// ---------------------------------------------------------------------------
__device__ __forceinline__
void transpose_tile(const float* __restrict__ src, int srcStride,
                    __bf16* __restrict__ dst, int dstStride,
                    int rb, int cb, float t[32][33]) {
    int tx = threadIdx.x & 31, ty = threadIdx.x >> 5;
    #pragma unroll
    for (int i = 0; i < 32; i += 8)
        t[ty + i][tx] = src[(long long)(rb + ty + i) * srcStride + cb + tx];
    __syncthreads();
    #pragma unroll
    for (int i = 0; i < 32; i += 8)
        dst[(long long)(cb + ty + i) * dstStride + rb + tx] = (__bf16)t[tx][ty + i];
}

__global__ __launch_bounds__(256)
void prep2_kernel(const float* __restrict__ Wq, const float* __restrict__ Wkv,
                  const float* __restrict__ wop,
                  const float* __restrict__ null_v, const float* __restrict__ null_k,
                  __bf16* __restrict__ wqt, __bf16* __restrict__ wkt,
                  __bf16* __restrict__ wvpt, float* __restrict__ vpnull,
                  __bf16* __restrict__ k_bf) {
    __shared__ float t[32][33];
    int b = blockIdx.x;
    if (b < 1536) {
        int rb = (b >> 4) * 32, cb = (b & 15) * 32;
        transpose_tile(Wq, INNER, wqt, DH, rb, cb, t);
    } else if (b < 2048) {
        int bi = b - 1536;
        int rb = (bi >> 4) * 32, cb = (bi & 15) * 32;
        transpose_tile(Wkv, 2 * INNER, wkt, DC, rb, cb, t);
    } else if (b < 2080) {
        int tt = (b - 2048) * 256 + threadIdx.x;   // 0..8191
        int k = tt >> 3, h = tt & 7;
        const float* src = Wkv + (long long)k * (2 * INNER) + INNER + h * 64;
        const float* wv  = wop + h * 64;
        float s = 0.f;
        #pragma unroll 16
        for (int d = 0; d < 64; ++d) s += src[d] * wv[d];
        wvpt[h * 1024 + k] = (__bf16)s;
    } else {
        for (int i = threadIdx.x; i < 8 * 1024; i += 256)
            wvpt[8 * 1024 + i] = (__bf16)0.f;
        for (int i = threadIdx.x; i < NCTX * INNER; i += 256) {
            int c = i >> 9, d = i & 511;
            k_bf[(long long)(c * 128) * INNER + d] = (__bf16)null_k[d];
        }
        if (threadIdx.x < 8) {
            int h = threadIdx.x;
            float s = 0.f;
            #pragma unroll 16
            for (int d = 0; d < 64; ++d) s += null_v[h * 64 + d] * wop[h * 64 + d];
            vpnull[h] = s;
        }
    }
}

// ---------------------------------------------------------------------------
// K3: merged projection GEMM (bf16 MFMA, 128x128 tile, BK=32, global_load_lds)
// blocks [0,224):   q split-K=8 -> fp32 slice qsl[s][896][512]
// blocks [224,480): k GEMM 8192x512x1024 -> bf16 KBF scatter; n0==0 blocks
//                   also compute vp via an extra WVPT B-fragment (cols 0..7)
// ---------------------------------------------------------------------------
__global__ __launch_bounds__(256)
void proj_kernel(const __bf16* __restrict__ ANQ, const __bf16* __restrict__ WQT,
                 const __bf16* __restrict__ ANKV, const __bf16* __restrict__ WKT,
                 const __bf16* __restrict__ WVPT,
                 float* __restrict__ qsl, __bf16* __restrict__ kout,
                 float* __restrict__ vpm) {
    __shared__ __align__(16) __bf16 As[128 * 32];
    __shared__ __align__(16) __bf16 Bs[128 * 32];
    int b = blockIdx.x;
    int tid = threadIdx.x;
    int lane = tid & 63, w = tid >> 6;
    int n16 = lane & 15, quad = lane >> 4;
    int wr = (w >> 1) * 64, wc = (w & 1) * 64;

    const __bf16 *A, *B;
    int K, kbeg, kend, mode, slice = 0;
    long long m0, n0;
    if (b < 224) {
        mode = 0; slice = b / 28;
        int rem = b % 28;
        m0 = (long long)(rem % 7) * 128;
        n0 = (long long)(rem / 7) * 128;
        K = DH; kbeg = slice * 384; kend = kbeg + 384;
        A = ANQ; B = WQT;
    } else {
        mode = 1;
        int b2 = b - 224;
        m0 = (long long)(b2 & 63) * 128;
        n0 = (long long)(b2 >> 6) * 128;
        K = DC; kbeg = 0; kend = DC;
        A = ANKV; B = WKT;
    }
    bool dovp = (mode == 1) && (n0 == 0);

    const __bf16* aG = A + (m0 + (tid >> 2)) * K + (tid & 3) * 8;
    const __bf16* bG = B + (n0 + (tid >> 2)) * K + (tid & 3) * 8;
    __bf16* aL = As + tid * 8;
    __bf16* bL = Bs + tid * 8;

    f32x4 acc[4][4], accv[4];
    const f32x4 z = {0.f, 0.f, 0.f, 0.f};
    #pragma unroll
    for (int i = 0; i < 4; ++i) {
        accv[i] = z;
        #pragma unroll
        for (int j = 0; j < 4; ++j) acc[i][j] = z;
    }

    for (int k0 = kbeg; k0 < kend; k0 += 32) {
        async_copy16(aG + k0, aL);
        async_copy16(aG + (long long)64 * K + k0, aL + 2048);
        async_copy16(bG + k0, bL);
        async_copy16(bG + (long long)64 * K + k0, bL + 2048);
        bf16x8 bv;
        if (dovp) bv = *(const bf16x8*)&WVPT[n16 * 1024 + k0 + quad * 8];
        __syncthreads();
        bf16x8 af[4], bfr[4];
        #pragma unroll
        for (int i = 0; i < 4; ++i)
            af[i]  = *(const bf16x8*)&As[(wr + i * 16 + n16) * 32 + quad * 8];
        #pragma unroll
        for (int j = 0; j < 4; ++j)
            bfr[j] = *(const bf16x8*)&Bs[(wc + j * 16 + n16) * 32 + quad * 8];
        #pragma unroll
        for (int i = 0; i < 4; ++i)
            #pragma unroll
            for (int j = 0; j < 4; ++j)
                acc[i][j] = __builtin_amdgcn_mfma_f32_16x16x32_bf16(af[i], bfr[j], acc[i][j], 0, 0, 0);
        if (dovp) {
            #pragma unroll
            for (int i = 0; i < 4; ++i)
                accv[i] = __builtin_amdgcn_mfma_f32_16x16x32_bf16(af[i], bv, accv[i], 0, 0, 0);
        }
        __syncthreads();
    }

    if (mode == 0) {
        float* qdst = qsl + (long long)slice * (N_SEQ * INNER);
        #pragma unroll
        for (int i = 0; i < 4; ++i)
            #pragma unroll
            for (int r = 0; r < 4; ++r) {
                long long gr = m0 + wr + i * 16 + quad * 4 + r;
                #pragma unroll
                for (int j = 0; j < 4; ++j) {
                    long long gc = n0 + wc + j * 16 + n16;
                    qdst[gr * INNER + gc] = acc[i][j][r];
                }
            }
    } else {
        #pragma unroll
        for (int i = 0; i < 4; ++i)
            #pragma unroll
            for (int r = 0; r < 4; ++r) {
                long long gr = m0 + wr + i * 16 + quad * 4 + r;
                if (gr >= MKV) continue;
                int cc = (int)(gr / JLEN), jj = (int)(gr % JLEN);
                #pragma unroll
                for (int j = 0; j < 4; ++j) {
                    long long gc = n0 + wc + j * 16 + n16;
                    kout[((long long)(cc * 128) + jj + 1) * INNER + gc] = (__bf16)acc[i][j][r];
                }
                if (dovp && n16 < 8) vpm[gr * 8 + n16] = accv[i][r];
            }
    }
}

// ---------------------------------------------------------------------------
// K4: reduce 8 q split-K slices -> bf16
// ---------------------------------------------------------------------------
__global__ void qreduce_kernel(const float* __restrict__ qsl, __bf16* __restrict__ qbf) {
    int t = blockIdx.x * 256 + threadIdx.x;   // 458752 total
    float s = 0.f;
    #pragma unroll
    for (int k = 0; k < 8; ++k) s += qsl[(long long)k * (N_SEQ * INNER) + t];
    qbf[t] = (__bf16)s;
}

// ---------------------------------------------------------------------------
// K5: attention via MFMA, no LDS. grid (7, NCTX*HEADS); each block 4 waves x
// 2 q-tiles of 16 rows. Per-tile (not per-row) softmax max: one 4-step
// shuffle; epilogue l,p butterflies batched across 4 rows.
// ---------------------------------------------------------------------------
__global__ __launch_bounds__(256)
void attn_mfma_kernel(const __bf16* __restrict__ qb, const __bf16* __restrict__ kb,
                      const float* __restrict__ vpm, const float* __restrict__ vpnull,
                      const int* __restrict__ mask, float* __restrict__ s_buf) {
    int ch = blockIdx.y;
    int h = ch & 7, c = ch >> 3;
    int tid = threadIdx.x;
    int lane = tid & 63, w = tid >> 6;
    int n16 = lane & 15, quad = lane >> 4;

    const __bf16* kbase = kb + (long long)(c * 128) * INNER + h * DHEAD;
    bf16x8 bF[8][2];
    #pragma unroll
    for (int t = 0; t < 8; ++t)
        #pragma unroll
        for (int s = 0; s < 2; ++s)
            bF[t][s] = *(const bf16x8*)(kbase + (long long)(t * 16 + n16) * INNER + s * 32 + quad * 8);

    float vpv[8], am[8];
    #pragma unroll
    for (int t = 0; t < 8; ++t) {
        int col = t * 16 + n16;
        vpv[t] = (col == 0) ? vpnull[h] : vpm[(long long)(c * JLEN + col - 1) * 8 + h];
        am[t]  = (col == 0) ? 0.f : (mask[col - 1] ? 0.f : -3.0e38f);
    }

    const __bf16* qbase = qb + h * DHEAD;
    const f32x4 zero = {0.f, 0.f, 0.f, 0.f};
    #pragma unroll
    for (int it2 = 0; it2 < 2; ++it2) {
        int it = blockIdx.x * 2 + it2;
        int r0 = (it * 4 + w) * 16;
        const __bf16* qrow = qbase + (long long)(r0 + n16) * INNER + quad * 8;
        bf16x8 aF0 = *(const bf16x8*)(qrow);
        bf16x8 aF1 = *(const bf16x8*)(qrow + 32);
        f32x4 acc[8];
        #pragma unroll
        for (int t = 0; t < 8; ++t) {
            acc[t] = __builtin_amdgcn_mfma_f32_16x16x32_bf16(aF0, bF[t][0], zero,   0, 0, 0);
            acc[t] = __builtin_amdgcn_mfma_f32_16x16x32_bf16(aF1, bF[t][1], acc[t], 0, 0, 0);
        }
        // per-tile max
        float mloc = -3.0e38f;
        #pragma unroll
        for (int t = 0; t < 8; ++t)
            #pragma unroll
            for (int r = 0; r < 4; ++r)
                mloc = fmaxf(mloc, acc[t][r] * 0.125f + am[t]);
        #pragma unroll
        for (int o = 1; o < 16; o <<= 1) mloc = fmaxf(mloc, __shfl_xor(mloc, o, 16));
        // exp + per-row partial sums
        float lr[4] = {0.f, 0.f, 0.f, 0.f}, pr[4] = {0.f, 0.f, 0.f, 0.f};
        #pragma unroll
        for (int t = 0; t < 8; ++t) {
            #pragma unroll
            for (int r = 0; r < 4; ++r) {
                float e = __expf(acc[t][r] * 0.125f + am[t] - mloc);
                lr[r] += e; pr[r] += e * vpv[t];
            }
        }
        #pragma unroll
        for (int o = 1; o < 16; o <<= 1) {
            #pragma unroll
            for (int r = 0; r < 4; ++r) {
                lr[r] += __shfl_xor(lr[r], o, 16);
                pr[r] += __shfl_xor(pr[r], o, 16);
            }
        }
        if (n16 == 0) {
            #pragma unroll
            for (int r = 0; r < 4; ++r)
                s_buf[(long long)ch * N_SEQ + r0 + quad * 4 + r] = pr[r] / lr[r];
        }
    }
}

// ---------------------------------------------------------------------------
// K6: final: pred[n,c] = softplus(e_dot[n] + sum_h s[c,h,n] + bop + bp)
// ---------------------------------------------------------------------------
__global__ void final_kernel(const float* __restrict__ s_buf,
                             const float* __restrict__ e_dot,
                             const float* __restrict__ bop,
                             const float* __restrict__ bp,
                             float* __restrict__ out) {
    int t = blockIdx.x * blockDim.x + threadIdx.x;
    if (t >= N_SEQ * NCTX) return;
    int n = t >> 6, c = t & 63;
    float s = 0.f;
    #pragma unroll
    for (int h = 0; h < HEADS; ++h) s += s_buf[((long long)(c * HEADS + h)) * N_SEQ + n];
    float x = e_dot[n] + s + *bop + *bp;
    out[t] = fmaxf(x, 0.f) + log1pf(__expf(-fabsf(x)));
}

// ---------------------------------------------------------------------------
extern "C" void kernel_launch(void* const* d_in, const int* in_sizes, int n_in,
                              void* d_out, int out_size, void* d_ws, size_t ws_size,
                              hipStream_t stream) {
    const float* emb   = (const float*)d_in[0];
    const float* ctx   = (const float*)d_in[1];
    const int*   cmask = (const int*)  d_in[2];
    const float* qg    = (const float*)d_in[3];
    const float* qb_   = (const float*)d_in[4];
    const float* kvg   = (const float*)d_in[5];
    const float* kvb   = (const float*)d_in[6];
    const float* Wq    = (const float*)d_in[7];
    const float* Wkv   = (const float*)d_in[8];
    const float* nullk = (const float*)d_in[9];
    const float* nullv = (const float*)d_in[10];
    const float* Wo    = (const float*)d_in[11];
    const float* bo    = (const float*)d_in[12];
    const float* Wp    = (const float*)d_in[13];
    const float* bp    = (const float*)d_in[14];
    float* out  = (float*)d_out;
    float* ws_f = (float*)d_ws;

    float*  EDOT   = ws_f + OFF_EDOT;
    __bf16* QBF    = (__bf16*)(ws_f + OFF_QBF);
    __bf16* KBF    = (__bf16*)(ws_f + OFF_KBF);
    float*  VPM    = ws_f + OFF_VPM;
    float*  VPNULL = ws_f + OFF_VPNULL;
    float*  WOP    = ws_f + OFF_WOP;
    float*  BOP    = ws_f + OFF_BOP;
    float*  SBUF   = ws_f + OFF_SBUF;
    __bf16* ANQ    = (__bf16*)(ws_f + OFF_ANQ);
    __bf16* ANKV   = (__bf16*)(ws_f + OFF_ANKV);
    __bf16* WQT    = (__bf16*)(ws_f + OFF_WQT);
    __bf16* WKT    = (__bf16*)(ws_f + OFF_WKT);
    __bf16* WVPT   = (__bf16*)(ws_f + OFF_WVPT);
    float*  QSL    = ws_f + OFF_QSL;

    ln_wop_kernel<<<N_SEQ + MKV + INNER + 1, 256, 0, stream>>>(
        emb, ctx, qg, qb_, kvg, kvb, Wp, Wo, bo, ANQ, ANKV, EDOT, WOP, BOP);
    prep2_kernel<<<2081, 256, 0, stream>>>(
        Wq, Wkv, WOP, nullv, nullk, WQT, WKT, WVPT, VPNULL, KBF);
    proj_kernel<<<480, 256, 0, stream>>>(ANQ, WQT, ANKV, WKT, WVPT, QSL, KBF, VPM);
    qreduce_kernel<<<(N_SEQ * INNER) / 256, 256, 0, stream>>>(QSL, QBF);
    attn_mfma_kernel<<<dim3(7, NCTX * HEADS), 256, 0, stream>>>(
        QBF, KBF, VPM, VPNULL, cmask, SBUF);
    final_kernel<<<(N_SEQ * NCTX + 255) / 256, 256, 0, stream>>>(SBUF, EDOT, BOP, bp, out);
}

// Round 6
// 216.561 us; speedup vs baseline: 1.1077x; 1.1077x over previous
//
#include <hip/hip_runtime.h>
#include <math.h>

// ---------------------------------------------------------------------------
// Problem constants
// ---------------------------------------------------------------------------
#define N_SEQ   896
#define DH      3072
#define NCTX    64
#define JLEN    127
#define DC      1024
#define HEADS   8
#define DHEAD   64
#define INNER   512   // HEADS*DHEAD
#define MKV     8128  // NCTX*JLEN
#define MKVPAD  8192

typedef __bf16 bf16x8 __attribute__((ext_vector_type(8)));
typedef float  f32x4  __attribute__((ext_vector_type(4)));

// workspace float offsets
#define OFF_EDOT   0LL
#define OFF_QBF    (OFF_EDOT + N_SEQ)
#define OFF_KBF    (OFF_QBF  + (long long)N_SEQ*INNER/2)     // bf16 896x512
#define OFF_VPM    (OFF_KBF  + (long long)NCTX*128*INNER/2)  // fp32 8128x8
#define OFF_VPNULL (OFF_VPM  + (long long)MKV*8)
#define OFF_WOP    (OFF_VPNULL + 8)
#define OFF_BOP    (OFF_WOP  + INNER)
#define OFF_SBUF   (OFF_BOP  + 16)                           // fp32 64*8*896
#define OFF_ANQ    (OFF_SBUF + (long long)NCTX*HEADS*N_SEQ)  // bf16 896x3072
#define OFF_ANKV   (OFF_ANQ  + (long long)N_SEQ*DH/2)        // bf16 8192x1024
#define OFF_WQT    (OFF_ANKV + (long long)MKVPAD*DC/2)       // bf16 512x3072
#define OFF_WKT    (OFF_WQT  + (long long)INNER*DH/2)        // bf16 512x1024
#define OFF_WVPT   (OFF_WKT  + (long long)INNER*DC/2)        // bf16 16x1024
#define OFF_QSL    (OFF_WVPT + 16*1024/2)                    // fp32 8 x 896x512

// ---------------------------------------------------------------------------
// async global->LDS 16B helper
// ---------------------------------------------------------------------------
__device__ __forceinline__ void async_copy16(const __bf16* g, __bf16* l) {
    __builtin_amdgcn_global_load_lds(
        (const __attribute__((address_space(1))) unsigned int*)g,
        (__attribute__((address_space(3))) unsigned int*)l,
        16, 0, 0);
}

// ---------------------------------------------------------------------------
// LN row helper: stats + normalize + bf16 convert (+ optional Wp dot)
// ---------------------------------------------------------------------------
template <int P>
__device__ __forceinline__
void ln_row(const float* __restrict__ x,
            const float* __restrict__ gamma, const float* __restrict__ beta,
            const float* __restrict__ wp,
            __bf16* __restrict__ o, float* __restrict__ dotout) {
    const int K = P * 1024;
    float4 xv[P];
    float s = 0.f, ss = 0.f, dp = 0.f;
    #pragma unroll
    for (int p = 0; p < P; ++p) {
        xv[p] = *(const float4*)&x[p * 1024 + threadIdx.x * 4];
        s  += xv[p].x + xv[p].y + xv[p].z + xv[p].w;
        ss += xv[p].x * xv[p].x + xv[p].y * xv[p].y
            + xv[p].z * xv[p].z + xv[p].w * xv[p].w;
        if (wp) {
            float4 w4 = *(const float4*)&wp[p * 1024 + threadIdx.x * 4];
            dp += xv[p].x * w4.x + xv[p].y * w4.y + xv[p].z * w4.z + xv[p].w * w4.w;
        }
    }
    #pragma unroll
    for (int ofs = 32; ofs > 0; ofs >>= 1) {
        s  += __shfl_down(s,  ofs);
        ss += __shfl_down(ss, ofs);
        dp += __shfl_down(dp, ofs);
    }
    __shared__ float red[3][4];
    __shared__ float sh_mu, sh_rstd;
    int lane = threadIdx.x & 63, w = threadIdx.x >> 6;
    if (lane == 0) { red[0][w] = s; red[1][w] = ss; red[2][w] = dp; }
    __syncthreads();
    if (threadIdx.x == 0) {
        float S  = red[0][0] + red[0][1] + red[0][2] + red[0][3];
        float SS = red[1][0] + red[1][1] + red[1][2] + red[1][3];
        float m = S / K;
        sh_mu = m;
        sh_rstd = rsqrtf(SS / K - m * m + 1e-5f);
        if (dotout) *dotout = red[2][0] + red[2][1] + red[2][2] + red[2][3];
    }
    __syncthreads();
    float m = sh_mu, r = sh_rstd;
    #pragma unroll
    for (int p = 0; p < P; ++p) {
        int col = p * 1024 + threadIdx.x * 4;
        float4 g4 = *(const float4*)&gamma[col];
        float4 b4 = *(const float4*)&beta[col];
        __bf16 ov[4];
        ov[0] = (__bf16)((xv[p].x - m) * r * g4.x + b4.x);
        ov[1] = (__bf16)((xv[p].y - m) * r * g4.y + b4.y);
        ov[2] = (__bf16)((xv[p].z - m) * r * g4.z + b4.z);
        ov[3] = (__bf16)((xv[p].w - m) * r * g4.w + b4.w);
        *(ushort4*)&o[col] = *(ushort4*)ov;
    }
}

// ---------------------------------------------------------------------------
// K1: fused ln_q (896) + ln_kv (8128) + wop/bop (513) by block range
// ---------------------------------------------------------------------------
__global__ __launch_bounds__(256)
void ln_wop_kernel(const float* __restrict__ emb, const float* __restrict__ ctx,
                   const float* __restrict__ qg, const float* __restrict__ qb,
                   const float* __restrict__ kvg, const float* __restrict__ kvb,
                   const float* __restrict__ Wp, const float* __restrict__ Wo,
                   const float* __restrict__ bo,
                   __bf16* __restrict__ anq, __bf16* __restrict__ ankv,
                   float* __restrict__ edot, float* __restrict__ wop,
                   float* __restrict__ bop) {
    int b = blockIdx.x;
    if (b < N_SEQ) {
        ln_row<3>(emb + (long long)b * DH, qg, qb, Wp,
                  anq + (long long)b * DH, edot + b);
    } else if (b < N_SEQ + MKV) {
        int r = b - N_SEQ;
        ln_row<1>(ctx + (long long)r * DC, kvg, kvb, nullptr,
                  ankv + (long long)r * DC, nullptr);
    } else {
        int r = b - (N_SEQ + MKV);   // 0..512
        const float* src = (r < INNER) ? (Wo + (long long)r * DH) : bo;
        float s = 0.f;
        for (int k = threadIdx.x; k < DH; k += 256) s += src[k] * Wp[k];
        #pragma unroll
        for (int o = 32; o > 0; o >>= 1) s += __shfl_down(s, o);
        __shared__ float red2[4];
        int lane = threadIdx.x & 63, w = threadIdx.x >> 6;
        if (lane == 0) red2[w] = s;
        __syncthreads();
        if (threadIdx.x == 0) {
            float S = red2[0] + red2[1] + red2[2] + red2[3];
            if (r < INNER) wop[r] = S; else *bop = S;
        }
    }
}

// ---------------------------------------------------------------------------
// K2: fused weight prep: WQT transpose (1536) + WKT transpose (512) +
//     wvpt (32) + null_k/vpnull/zero (1)
// ---------------------------------------------------------------------------
__device__ __forceinline__
void transpose_tile(const float* __restrict__ src, int srcStride,
                    __bf16* __restrict__ dst, int dstStride,
                    int rb, int cb, float t[32][33]) {
    int tx = threadIdx.x & 31, ty = threadIdx.x >> 5;
    #pragma unroll
    for (int i = 0; i < 32; i += 8)
        t[ty + i][tx] = src[(long long)(rb + ty + i) * srcStride + cb + tx];
    __syncthreads();
    #pragma unroll
    for (int i = 0; i < 32; i += 8)
        dst[(long long)(cb + ty + i) * dstStride + rb + tx] = (__bf16)t[tx][ty + i];
}

__global__ __launch_bounds__(256)
void prep2_kernel(const float* __restrict__ Wq, const float* __restrict__ Wkv,
                  const float* __restrict__ wop,
                  const float* __restrict__ null_v, const float* __restrict__ null_k,
                  __bf16* __restrict__ wqt, __bf16* __restrict__ wkt,
                  __bf16* __restrict__ wvpt, float* __restrict__ vpnull,
                  __bf16* __restrict__ k_bf) {
    __shared__ float t[32][33];
    int b = blockIdx.x;
    if (b < 1536) {
        int rb = (b >> 4) * 32, cb = (b & 15) * 32;
        transpose_tile(Wq, INNER, wqt, DH, rb, cb, t);
    } else if (b < 2048) {
        int bi = b - 1536;
        int rb = (bi >> 4) * 32, cb = (bi & 15) * 32;
        transpose_tile(Wkv, 2 * INNER, wkt, DC, rb, cb, t);
    } else if (b < 2080) {
        int tt = (b - 2048) * 256 + threadIdx.x;   // 0..8191
        int k = tt >> 3, h = tt & 7;
        const float* src = Wkv + (long long)k * (2 * INNER) + INNER + h * 64;
        const float* wv  = wop + h * 64;
        float s = 0.f;
        #pragma unroll 16
        for (int d = 0; d < 64; ++d) s += src[d] * wv[d];
        wvpt[h * 1024 + k] = (__bf16)s;
    } else {
        for (int i = threadIdx.x; i < 8 * 1024; i += 256)
            wvpt[8 * 1024 + i] = (__bf16)0.f;
        for (int i = threadIdx.x; i < NCTX * INNER; i += 256) {
            int c = i >> 9, d = i & 511;
            k_bf[(long long)(c * 128) * INNER + d] = (__bf16)null_k[d];
        }
        if (threadIdx.x < 8) {
            int h = threadIdx.x;
            float s = 0.f;
            #pragma unroll 16
            for (int d = 0; d < 64; ++d) s += null_v[h * 64 + d] * wop[h * 64 + d];
            vpnull[h] = s;
        }
    }
}

// ---------------------------------------------------------------------------
// K3: merged projection GEMM (bf16 MFMA, 128x128 tile, BK=32, global_load_lds)
// blocks [0,224):   q split-K=8 -> fp32 slice qsl[s][896][512]
// blocks [224,480): k GEMM 8192x512x1024 -> bf16 KBF scatter; n0==0 blocks
//                   also compute vp via an extra WVPT B-fragment (cols 0..7)
// ---------------------------------------------------------------------------
__global__ __launch_bounds__(256)
void proj_kernel(const __bf16* __restrict__ ANQ, const __bf16* __restrict__ WQT,
                 const __bf16* __restrict__ ANKV, const __bf16* __restrict__ WKT,
                 const __bf16* __restrict__ WVPT,
                 float* __restrict__ qsl, __bf16* __restrict__ kout,
                 float* __restrict__ vpm) {
    __shared__ __align__(16) __bf16 As[128 * 32];
    __shared__ __align__(16) __bf16 Bs[128 * 32];
    int b = blockIdx.x;
    int tid = threadIdx.x;
    int lane = tid & 63, w = tid >> 6;
    int n16 = lane & 15, quad = lane >> 4;
    int wr = (w >> 1) * 64, wc = (w & 1) * 64;

    const __bf16 *A, *B;
    int K, kbeg, kend, mode, slice = 0;
    long long m0, n0;
    if (b < 224) {
        mode = 0; slice = b / 28;
        int rem = b % 28;
        m0 = (long long)(rem % 7) * 128;
        n0 = (long long)(rem / 7) * 128;
        K = DH; kbeg = slice * 384; kend = kbeg + 384;
        A = ANQ; B = WQT;
    } else {
        mode = 1;
        int b2 = b - 224;
        m0 = (long long)(b2 & 63) * 128;
        n0 = (long long)(b2 >> 6) * 128;
        K = DC; kbeg = 0; kend = DC;
        A = ANKV; B = WKT;
    }
    bool dovp = (mode == 1) && (n0 == 0);

    const __bf16* aG = A + (m0 + (tid >> 2)) * K + (tid & 3) * 8;
    const __bf16* bG = B + (n0 + (tid >> 2)) * K + (tid & 3) * 8;
    __bf16* aL = As + tid * 8;
    __bf16* bL = Bs + tid * 8;

    f32x4 acc[4][4], accv[4];
    const f32x4 z = {0.f, 0.f, 0.f, 0.f};
    #pragma unroll
    for (int i = 0; i < 4; ++i) {
        accv[i] = z;
        #pragma unroll
        for (int j = 0; j < 4; ++j) acc[i][j] = z;
    }

    for (int k0 = kbeg; k0 < kend; k0 += 32) {
        async_copy16(aG + k0, aL);
        async_copy16(aG + (long long)64 * K + k0, aL + 2048);
        async_copy16(bG + k0, bL);
        async_copy16(bG + (long long)64 * K + k0, bL + 2048);
        bf16x8 bv;
        if (dovp) bv = *(const bf16x8*)&WVPT[n16 * 1024 + k0 + quad * 8];
        __syncthreads();
        bf16x8 af[4], bfr[4];
        #pragma unroll
        for (int i = 0; i < 4; ++i)
            af[i]  = *(const bf16x8*)&As[(wr + i * 16 + n16) * 32 + quad * 8];
        #pragma unroll
        for (int j = 0; j < 4; ++j)
            bfr[j] = *(const bf16x8*)&Bs[(wc + j * 16 + n16) * 32 + quad * 8];
        #pragma unroll
        for (int i = 0; i < 4; ++i)
            #pragma unroll
            for (int j = 0; j < 4; ++j)
                acc[i][j] = __builtin_amdgcn_mfma_f32_16x16x32_bf16(af[i], bfr[j], acc[i][j], 0, 0, 0);
        if (dovp) {
            #pragma unroll
            for (int i = 0; i < 4; ++i)
                accv[i] = __builtin_amdgcn_mfma_f32_16x16x32_bf16(af[i], bv, accv[i], 0, 0, 0);
        }
        __syncthreads();
    }

    if (mode == 0) {
        float* qdst = qsl + (long long)slice * (N_SEQ * INNER);
        #pragma unroll
        for (int i = 0; i < 4; ++i)
            #pragma unroll
            for (int r = 0; r < 4; ++r) {
                long long gr = m0 + wr + i * 16 + quad * 4 + r;
                #pragma unroll
                for (int j = 0; j < 4; ++j) {
                    long long gc = n0 + wc + j * 16 + n16;
                    qdst[gr * INNER + gc] = acc[i][j][r];
                }
            }
    } else {
        #pragma unroll
        for (int i = 0; i < 4; ++i)
            #pragma unroll
            for (int r = 0; r < 4; ++r) {
                long long gr = m0 + wr + i * 16 + quad * 4 + r;
                if (gr >= MKV) continue;
                int cc = (int)(gr / JLEN), jj = (int)(gr % JLEN);
                #pragma unroll
                for (int j = 0; j < 4; ++j) {
                    long long gc = n0 + wc + j * 16 + n16;
                    kout[((long long)(cc * 128) + jj + 1) * INNER + gc] = (__bf16)acc[i][j][r];
                }
                if (dovp && n16 < 8) vpm[gr * 8 + n16] = accv[i][r];
            }
    }
}

// ---------------------------------------------------------------------------
// K4: reduce 8 q split-K slices -> bf16
// ---------------------------------------------------------------------------
__global__ void qreduce_kernel(const float* __restrict__ qsl, __bf16* __restrict__ qbf) {
    int t = blockIdx.x * 256 + threadIdx.x;   // 458752 total
    float s = 0.f;
    #pragma unroll
    for (int k = 0; k < 8; ++k) s += qsl[(long long)k * (N_SEQ * INNER) + t];
    qbf[t] = (__bf16)s;
}

// ---------------------------------------------------------------------------
// K5: attention via MFMA. grid (7, NCTX*HEADS). K-head tile staged into LDS
// cooperatively (coalesced), fragments built via ds_read_b128 (padded rows,
// max 2-way conflict = free). vp/mask staged via LDS. Each wave: 2 q-tiles,
// q loads issued up front; per-tile softmax max.
// ---------------------------------------------------------------------------
#define KROW 72   // LDS row stride in bf16 (64 data + 8 pad)

__global__ __launch_bounds__(256)
void attn_mfma_kernel(const __bf16* __restrict__ qb, const __bf16* __restrict__ kb,
                      const float* __restrict__ vpm, const float* __restrict__ vpnull,
                      const int* __restrict__ mask, float* __restrict__ s_buf) {
    __shared__ __align__(16) __bf16 ksh[128 * KROW];
    __shared__ float vpsh[128];
    __shared__ float amsh[128];
    int ch = blockIdx.y;
    int h = ch & 7, c = ch >> 3;
    int tid = threadIdx.x;
    int lane = tid & 63, w = tid >> 6;
    int n16 = lane & 15, quad = lane >> 4;

    // cooperative K stage: 128 rows x 128 B, fully coalesced 16 B chunks
    const __bf16* kbase = kb + (long long)(c * 128) * INNER + h * DHEAD;
    #pragma unroll
    for (int p = 0; p < 4; ++p) {
        int chunk = tid + p * 256;          // 0..1023
        int row = chunk >> 3, o = chunk & 7;
        bf16x8 v = *(const bf16x8*)(kbase + (long long)row * INNER + o * 8);
        *(bf16x8*)&ksh[row * KROW + o * 8] = v;
    }
    if (tid < 128) {
        vpsh[tid] = (tid == 0) ? vpnull[h] : vpm[(long long)(c * JLEN + tid - 1) * 8 + h];
        amsh[tid] = (tid == 0) ? 0.f : (mask[tid - 1] ? 0.f : -3.0e38f);
    }
    __syncthreads();

    bf16x8 bF[8][2];
    #pragma unroll
    for (int t = 0; t < 8; ++t)
        #pragma unroll
        for (int s = 0; s < 2; ++s)
            bF[t][s] = *(const bf16x8*)&ksh[(t * 16 + n16) * KROW + s * 32 + quad * 8];

    float vpv[8], am[8];
    #pragma unroll
    for (int t = 0; t < 8; ++t) {
        vpv[t] = vpsh[t * 16 + n16];
        am[t]  = amsh[t * 16 + n16];
    }

    // issue both q-tile loads up front
    const __bf16* qbase = qb + h * DHEAD;
    bf16x8 aF[2][2];
    int r0s[2];
    #pragma unroll
    for (int it2 = 0; it2 < 2; ++it2) {
        int tile = blockIdx.x * 8 + it2 * 4 + w;   // 0..55
        r0s[it2] = tile * 16;
        const __bf16* qrow = qbase + (long long)(r0s[it2] + n16) * INNER + quad * 8;
        aF[it2][0] = *(const bf16x8*)(qrow);
        aF[it2][1] = *(const bf16x8*)(qrow + 32);
    }

    const f32x4 zero = {0.f, 0.f, 0.f, 0.f};
    #pragma unroll
    for (int it2 = 0; it2 < 2; ++it2) {
        int r0 = r0s[it2];
        f32x4 acc[8];
        #pragma unroll
        for (int t = 0; t < 8; ++t) {
            acc[t] = __builtin_amdgcn_mfma_f32_16x16x32_bf16(aF[it2][0], bF[t][0], zero,   0, 0, 0);
            acc[t] = __builtin_amdgcn_mfma_f32_16x16x32_bf16(aF[it2][1], bF[t][1], acc[t], 0, 0, 0);
        }
        // per-tile max
        float mloc = -3.0e38f;
        #pragma unroll
        for (int t = 0; t < 8; ++t)
            #pragma unroll
            for (int r = 0; r < 4; ++r)
                mloc = fmaxf(mloc, acc[t][r] * 0.125f + am[t]);
        #pragma unroll
        for (int o = 1; o < 16; o <<= 1) mloc = fmaxf(mloc, __shfl_xor(mloc, o, 16));
        // exp + per-row partial sums
        float lr[4] = {0.f, 0.f, 0.f, 0.f}, pr[4] = {0.f, 0.f, 0.f, 0.f};
        #pragma unroll
        for (int t = 0; t < 8; ++t) {
            #pragma unroll
            for (int r = 0; r < 4; ++r) {
                float e = __expf(acc[t][r] * 0.125f + am[t] - mloc);
                lr[r] += e; pr[r] += e * vpv[t];
            }
        }
        #pragma unroll
        for (int o = 1; o < 16; o <<= 1) {
            #pragma unroll
            for (int r = 0; r < 4; ++r) {
                lr[r] += __shfl_xor(lr[r], o, 16);
                pr[r] += __shfl_xor(pr[r], o, 16);
            }
        }
        if (n16 == 0) {
            #pragma unroll
            for (int r = 0; r < 4; ++r)
                s_buf[(long long)ch * N_SEQ + r0 + quad * 4 + r] = pr[r] / lr[r];
        }
    }
}

// ---------------------------------------------------------------------------
// K6: final: pred[n,c] = softplus(e_dot[n] + sum_h s[c,h,n] + bop + bp)
// ---------------------------------------------------------------------------
__global__ void final_kernel(const float* __restrict__ s_buf,
                             const float* __restrict__ e_dot,
                             const float* __restrict__ bop,
                             const float* __restrict__ bp,
                             float* __restrict__ out) {
    int t = blockIdx.x * blockDim.x + threadIdx.x;
    if (t >= N_SEQ * NCTX) return;
    int n = t >> 6, c = t & 63;
    float s = 0.f;
    #pragma unroll
    for (int h = 0; h < HEADS; ++h) s += s_buf[((long long)(c * HEADS + h)) * N_SEQ + n];
    float x = e_dot[n] + s + *bop + *bp;
    out[t] = fmaxf(x, 0.f) + log1pf(__expf(-fabsf(x)));
}

// ---------------------------------------------------------------------------
extern "C" void kernel_launch(void* const* d_in, const int* in_sizes, int n_in,
                              void* d_out, int out_size, void* d_ws, size_t ws_size,
                              hipStream_t stream) {
    const float* emb   = (const float*)d_in[0];
    const float* ctx   = (const float*)d_in[1];
    const int*   cmask = (const int*)  d_in[2];
    const float* qg    = (const float*)d_in[3];
    const float* qb_   = (const float*)d_in[4];
    const float* kvg   = (const float*)d_in[5];
    const float* kvb   = (const float*)d_in[6];
    const float* Wq    = (const float*)d_in[7];
    const float* Wkv   = (const float*)d_in[8];
    const float* nullk = (const float*)d_in[9];
    const float* nullv = (const float*)d_in[10];
    const float* Wo    = (const float*)d_in[11];
    const float* bo    = (const float*)d_in[12];
    const float* Wp    = (const float*)d_in[13];
    const float* bp    = (const float*)d_in[14];
    float* out  = (float*)d_out;
    float* ws_f = (float*)d_ws;

    float*  EDOT   = ws_f + OFF_EDOT;
    __bf16* QBF    = (__bf16*)(ws_f + OFF_QBF);
    __bf16* KBF    = (__bf16*)(ws_f + OFF_KBF);
    float*  VPM    = ws_f + OFF_VPM;
    float*  VPNULL = ws_f + OFF_VPNULL;
    float*  WOP    = ws_f + OFF_WOP;
    float*  BOP    = ws_f + OFF_BOP;
    float*  SBUF   = ws_f + OFF_SBUF;
    __bf16* ANQ    = (__bf16*)(ws_f + OFF_ANQ);
    __bf16* ANKV   = (__bf16*)(ws_f + OFF_ANKV);
    __bf16* WQT    = (__bf16*)(ws_f + OFF_WQT);
    __bf16* WKT    = (__bf16*)(ws_f + OFF_WKT);
    __bf16* WVPT   = (__bf16*)(ws_f + OFF_WVPT);
    float*  QSL    = ws_f + OFF_QSL;

    ln_wop_kernel<<<N_SEQ + MKV + INNER + 1, 256, 0, stream>>>(
        emb, ctx, qg, qb_, kvg, kvb, Wp, Wo, bo, ANQ, ANKV, EDOT, WOP, BOP);
    prep2_kernel<<<2081, 256, 0, stream>>>(
        Wq, Wkv, WOP, nullv, nullk, WQT, WKT, WVPT, VPNULL, KBF);
    proj_kernel<<<480, 256, 0, stream>>>(ANQ, WQT, ANKV, WKT, WVPT, QSL, KBF, VPM);
    qreduce_kernel<<<(N_SEQ * INNER) / 256, 256, 0, stream>>>(QSL, QBF);
    attn_mfma_kernel<<<dim3(7, NCTX * HEADS), 256, 0, stream>>>(
        QBF, KBF, VPM, VPNULL, cmask, SBUF);
    final_kernel<<<(N_SEQ * NCTX + 255) / 256, 256, 0, stream>>>(SBUF, EDOT, BOP, bp, out);
}